// Round 2
// baseline (1246.808 us; speedup 1.0000x reference)
//
#include <hip/hip_runtime.h>
#include <hip/hip_bf16.h>

#define Bn 64
#define Tn 512
#define En 128
#define Hn 64
#define Gn 256   // 4*H
#define Cn 20

__device__ __forceinline__ float sigf(float x)      { return 1.f/(1.f+__expf(-x)); }
__device__ __forceinline__ float tanhfast(float x)  { return 2.f/(1.f+__expf(-2.f*x)) - 1.f; }

// ---------------------------------------------------------------------------
// Kernel A: Z0[b*T+t][j] = (word_emb[ids[b,t]] + pos_emb[t]) @ Wx_b0 + b_b0
// grid = (B*T)/64 blocks, 256 threads. 64 rows x 256 cols per block.
// ---------------------------------------------------------------------------
__global__ __launch_bounds__(256, 1) void emb_proj_kernel(
    const int* __restrict__ x, const float* __restrict__ word_emb,
    const float* __restrict__ pos_emb, const float* __restrict__ wx,
    const float* __restrict__ bias, float* __restrict__ z0)
{
  __shared__ float emb[64][En];     // 32 KB
  __shared__ float wxl[32][Gn];     // 32 KB
  const int tid  = threadIdx.x;
  const int row0 = blockIdx.x * 64;

  #pragma unroll
  for (int it = 0; it < 8; ++it) {
    int idx = it*256 + tid;           // 0..2047
    int rr  = idx >> 5;
    int e4  = (idx & 31) << 2;
    int r   = row0 + rr;
    int b   = r >> 9;
    int t   = r & (Tn-1);
    int id  = x[b*3*Tn + t];
    float4 we = *reinterpret_cast<const float4*>(&word_emb[(size_t)id*En + e4]);
    float4 pe = *reinterpret_cast<const float4*>(&pos_emb[(size_t)t*En + e4]);
    *reinterpret_cast<float4*>(&emb[rr][e4]) =
        make_float4(we.x+pe.x, we.y+pe.y, we.z+pe.z, we.w+pe.w);
  }

  const int jc = tid & 63;
  const int rg = tid >> 6;
  float acc[16][4];
  float4 bb = *reinterpret_cast<const float4*>(&bias[jc*4]);
  #pragma unroll
  for (int r = 0; r < 16; ++r) { acc[r][0]=bb.x; acc[r][1]=bb.y; acc[r][2]=bb.z; acc[r][3]=bb.w; }

  for (int ec = 0; ec < 4; ++ec) {
    __syncthreads();
    #pragma unroll
    for (int it = 0; it < 8; ++it) {
      int idx = it*256 + tid;
      int ee  = idx >> 6;
      int j4  = (idx & 63) << 2;
      *reinterpret_cast<float4*>(&wxl[ee][j4]) =
          *reinterpret_cast<const float4*>(&wx[(size_t)(ec*32+ee)*Gn + j4]);
    }
    __syncthreads();
    for (int ee = 0; ee < 32; ++ee) {
      float4 w = *reinterpret_cast<const float4*>(&wxl[ee][jc*4]);
      #pragma unroll
      for (int r = 0; r < 16; ++r) {
        float xv = emb[rg*16+r][ec*32+ee];
        acc[r][0] = fmaf(xv, w.x, acc[r][0]);
        acc[r][1] = fmaf(xv, w.y, acc[r][1]);
        acc[r][2] = fmaf(xv, w.z, acc[r][2]);
        acc[r][3] = fmaf(xv, w.w, acc[r][3]);
      }
    }
  }
  #pragma unroll
  for (int r = 0; r < 16; ++r) {
    size_t row = (size_t)row0 + rg*16 + r;
    *reinterpret_cast<float4*>(&z0[row*Gn + jc*4]) =
        make_float4(acc[r][0], acc[r][1], acc[r][2], acc[r][3]);
  }
}

// ---------------------------------------------------------------------------
// Kernel A2: ZX1[b*T+t][j] = hb0[b,t,:] @ Wx_b1 + b_b1   (M=32768,K=64,N=256)
// ---------------------------------------------------------------------------
__global__ __launch_bounds__(256, 1) void zx1_gemm_kernel(
    const float* __restrict__ hb0, const float* __restrict__ wx,
    const float* __restrict__ bias, float* __restrict__ zx1)
{
  __shared__ float xl[64][Hn];      // 16 KB
  __shared__ float wl[32][Gn];      // 32 KB
  const int tid  = threadIdx.x;
  const int row0 = blockIdx.x * 64;

  #pragma unroll
  for (int it = 0; it < 4; ++it) {
    int idx = it*256 + tid;          // 0..1023 float4s
    int rr  = idx >> 4;
    int e4  = (idx & 15) << 2;
    *reinterpret_cast<float4*>(&xl[rr][e4]) =
        *reinterpret_cast<const float4*>(&hb0[((size_t)row0+rr)*Hn + e4]);
  }

  const int jc = tid & 63;
  const int rg = tid >> 6;
  float acc[16][4];
  float4 bb = *reinterpret_cast<const float4*>(&bias[jc*4]);
  #pragma unroll
  for (int r = 0; r < 16; ++r) { acc[r][0]=bb.x; acc[r][1]=bb.y; acc[r][2]=bb.z; acc[r][3]=bb.w; }

  for (int kc = 0; kc < 2; ++kc) {
    __syncthreads();
    #pragma unroll
    for (int it = 0; it < 8; ++it) {
      int idx = it*256 + tid;
      int kk  = idx >> 6;
      int j4  = (idx & 63) << 2;
      *reinterpret_cast<float4*>(&wl[kk][j4]) =
          *reinterpret_cast<const float4*>(&wx[(size_t)(kc*32+kk)*Gn + j4]);
    }
    __syncthreads();
    for (int kk = 0; kk < 32; ++kk) {
      float4 w = *reinterpret_cast<const float4*>(&wl[kk][jc*4]);
      #pragma unroll
      for (int r = 0; r < 16; ++r) {
        float xv = xl[rg*16+r][kc*32+kk];
        acc[r][0] = fmaf(xv, w.x, acc[r][0]);
        acc[r][1] = fmaf(xv, w.y, acc[r][1]);
        acc[r][2] = fmaf(xv, w.z, acc[r][2]);
        acc[r][3] = fmaf(xv, w.w, acc[r][3]);
      }
    }
  }
  #pragma unroll
  for (int r = 0; r < 16; ++r) {
    size_t row = (size_t)row0 + rg*16 + r;
    *reinterpret_cast<float4*>(&zx1[row*Gn + jc*4]) =
        make_float4(acc[r][0], acc[r][1], acc[r][2], acc[r][3]);
  }
}

// ---------------------------------------------------------------------------
// Single-wave LSTM step macro: thread j owns h-lane j and gate columns
// {j, H+j, 2H+j, 3H+j}. Weights in registers; NO barriers anywhere.
// ---------------------------------------------------------------------------
#define LSTM_FMA_GROUP(k4)                                                  \
    {                                                                       \
      float4 hv = *reinterpret_cast<const float4*>(&h_lds[(k4)*4]);         \
      a0 = fmaf(hv.x, wc0[(k4)*4+0], a0); a1 = fmaf(hv.x, wc1[(k4)*4+0], a1); \
      a2 = fmaf(hv.x, wc2[(k4)*4+0], a2); a3 = fmaf(hv.x, wc3[(k4)*4+0], a3); \
      a0 = fmaf(hv.y, wc0[(k4)*4+1], a0); a1 = fmaf(hv.y, wc1[(k4)*4+1], a1); \
      a2 = fmaf(hv.y, wc2[(k4)*4+1], a2); a3 = fmaf(hv.y, wc3[(k4)*4+1], a3); \
      a0 = fmaf(hv.z, wc0[(k4)*4+2], a0); a1 = fmaf(hv.z, wc1[(k4)*4+2], a1); \
      a2 = fmaf(hv.z, wc2[(k4)*4+2], a2); a3 = fmaf(hv.z, wc3[(k4)*4+2], a3); \
      a0 = fmaf(hv.w, wc0[(k4)*4+3], a0); a1 = fmaf(hv.w, wc1[(k4)*4+3], a1); \
      a2 = fmaf(hv.w, wc2[(k4)*4+3], a2); a3 = fmaf(hv.w, wc3[(k4)*4+3], a3); \
    }

#define LSTM_BODY(mval, ZA)                                                 \
    if (mval) {                                                             \
      float a0 = ZA[0], a1 = ZA[1], a2 = ZA[2], a3 = ZA[3];                 \
      _Pragma("unroll")                                                     \
      for (int k4 = 0; k4 < Hn/4; ++k4) LSTM_FMA_GROUP(k4)                  \
      float ig = sigf(a0), fg = sigf(a1);                                   \
      float gg = tanhfast(a2), og = sigf(a3);                               \
      c = fmaf(fg, c, ig*gg);                                               \
      h = og * tanhfast(c);                                                 \
      h_lds[j] = h;                                                         \
    }

// ---------------------------------------------------------------------------
// Kernel B: layer b0 recurrence (reverse time). 1 wave per batch element.
// ---------------------------------------------------------------------------
__global__ __launch_bounds__(64, 1) void lstm_b0_wave(
    const int* __restrict__ x, const float* __restrict__ z0,
    const float* __restrict__ wh, float* __restrict__ hb0)
{
  const int b = blockIdx.x;
  const int j = threadIdx.x;        // 0..63
  __shared__ __align__(16) float h_lds[Hn];
  __shared__ int msk[Tn];

  float wc0[Hn], wc1[Hn], wc2[Hn], wc3[Hn];
  #pragma unroll
  for (int k = 0; k < Hn; ++k) {
    const float* wr = wh + (size_t)k*Gn;
    wc0[k] = wr[j]; wc1[k] = wr[Hn+j]; wc2[k] = wr[2*Hn+j]; wc3[k] = wr[3*Hn+j];
  }
  #pragma unroll
  for (int i = 0; i < Tn/Hn; ++i) msk[i*Hn + j] = x[b*3*Tn + 2*Tn + i*Hn + j];
  h_lds[j] = 0.f;
  float c = 0.f, h = 0.f;
  const float* zr   = z0  + (size_t)b*Tn*Gn;
  float*       hout = hb0 + (size_t)b*Tn*Hn;

  // prefetch depth 2, named registers (no runtime-indexed arrays)
  float zaA[4], zaB[4];
  { const float* p = zr + (size_t)511*Gn;
    zaA[0]=p[j]; zaA[1]=p[Hn+j]; zaA[2]=p[2*Hn+j]; zaA[3]=p[3*Hn+j]; }
  { const float* p = zr + (size_t)510*Gn;
    zaB[0]=p[j]; zaB[1]=p[Hn+j]; zaB[2]=p[2*Hn+j]; zaB[3]=p[3*Hn+j]; }

#define B0_STEP(t_, ZA)                                                     \
  {                                                                         \
    const int t5 = (t_);                                                    \
    int mval = msk[t5];                                                     \
    LSTM_BODY(mval, ZA)                                                     \
    hout[(size_t)t5*Hn + j] = h;                                            \
    int tp = t5 - 2; tp = tp < 0 ? 0 : tp;                                  \
    const float* pp = zr + (size_t)tp*Gn;                                   \
    ZA[0]=pp[j]; ZA[1]=pp[Hn+j]; ZA[2]=pp[2*Hn+j]; ZA[3]=pp[3*Hn+j];        \
  }

  for (int s = 0; s < Tn; s += 2) {
    B0_STEP(Tn-1-s, zaA);
    B0_STEP(Tn-2-s, zaB);
  }
#undef B0_STEP
}

// ---------------------------------------------------------------------------
// Kernel C: layer b1 recurrence (forward order, mask index T-1-t) + head.
// 1 wave per batch element; z = ZX1 precomputed.
// ---------------------------------------------------------------------------
__global__ __launch_bounds__(64, 1) void lstm_b1_wave_head(
    const int* __restrict__ x, const float* __restrict__ zx1,
    const float* __restrict__ wh, const float* __restrict__ dw,
    const float* __restrict__ db, float* __restrict__ out)
{
  const int b = blockIdx.x;
  const int j = threadIdx.x;        // 0..63
  __shared__ __align__(16) float h_lds[Hn];
  __shared__ float sm[2][32];
  __shared__ int msk[Tn];

  float wc0[Hn], wc1[Hn], wc2[Hn], wc3[Hn];
  #pragma unroll
  for (int k = 0; k < Hn; ++k) {
    const float* wr = wh + (size_t)k*Gn;
    wc0[k] = wr[j]; wc1[k] = wr[Hn+j]; wc2[k] = wr[2*Hn+j]; wc3[k] = wr[3*Hn+j];
  }
  #pragma unroll
  for (int i = 0; i < Tn/Hn; ++i) msk[i*Hn + j] = x[b*3*Tn + 2*Tn + i*Hn + j];
  h_lds[j] = 0.f;
  float c = 0.f, h = 0.f;
  const float* zr = zx1 + (size_t)b*Tn*Gn;

  float zaA[4], zaB[4];
  { const float* p = zr;
    zaA[0]=p[j]; zaA[1]=p[Hn+j]; zaA[2]=p[2*Hn+j]; zaA[3]=p[3*Hn+j]; }
  { const float* p = zr + (size_t)Gn;
    zaB[0]=p[j]; zaB[1]=p[Hn+j]; zaB[2]=p[2*Hn+j]; zaB[3]=p[3*Hn+j]; }

#define B1_STEP(t_, ZA)                                                     \
  {                                                                         \
    const int t5 = (t_);                                                    \
    int mval = msk[Tn-1-t5];   /* reference's double-flip misalignment */   \
    LSTM_BODY(mval, ZA)                                                     \
    int tp = t5 + 2; tp = tp > Tn-1 ? Tn-1 : tp;                            \
    const float* pp = zr + (size_t)tp*Gn;                                   \
    ZA[0]=pp[j]; ZA[1]=pp[Hn+j]; ZA[2]=pp[2*Hn+j]; ZA[3]=pp[3*Hn+j];        \
  }

  for (int s = 0; s < Tn; s += 2) {
    B1_STEP(s, zaA);
    B1_STEP(s+1, zaB);
  }
#undef B1_STEP

  // head: logits (C=20) + softmax, single wave, wave-synchronous LDS
  if (j < Cn) {
    float lg = db[j];
    #pragma unroll
    for (int k = 0; k < Hn; ++k) lg = fmaf(h_lds[k], dw[k*Cn + j], lg);
    sm[0][j] = lg;
  }
  if (j < Cn) {
    float m = sm[0][0];
    #pragma unroll
    for (int k = 1; k < Cn; ++k) m = fmaxf(m, sm[0][k]);
    float e = __expf(sm[0][j] - m);
    sm[1][j] = e;
    float ssum = 0.f;
    #pragma unroll
    for (int k = 0; k < Cn; ++k) ssum += sm[1][k];
    out[b*Cn + j] = e / ssum;
  }
}

// ---------------------------------------------------------------------------
extern "C" void kernel_launch(void* const* d_in, const int* in_sizes, int n_in,
                              void* d_out, int out_size, void* d_ws, size_t ws_size,
                              hipStream_t stream)
{
  const int*   x        = (const int*)  d_in[0];
  const float* word_emb = (const float*)d_in[1];
  const float* pos_emb  = (const float*)d_in[2];
  // forward-branch weights d_in[3..8] are dead code in the reference
  const float* wx_b0    = (const float*)d_in[9];
  const float* wh_b0    = (const float*)d_in[10];
  const float* b_b0     = (const float*)d_in[11];
  const float* wx_b1    = (const float*)d_in[12];
  const float* wh_b1    = (const float*)d_in[13];
  const float* b_b1     = (const float*)d_in[14];
  const float* dw       = (const float*)d_in[15];
  const float* db       = (const float*)d_in[16];
  float* out = (float*)d_out;

  float* z0  = (float*)d_ws;                    // B*T*256 f32 = 33.5 MB (reused as ZX1)
  float* hb0 = z0 + (size_t)Bn*Tn*Gn;           // B*T*64  f32 =  8.4 MB

  emb_proj_kernel<<<dim3((Bn*Tn)/64), dim3(256), 0, stream>>>(
      x, word_emb, pos_emb, wx_b0, b_b0, z0);
  lstm_b0_wave<<<dim3(Bn), dim3(64), 0, stream>>>(x, z0, wh_b0, hb0);
  zx1_gemm_kernel<<<dim3((Bn*Tn)/64), dim3(256), 0, stream>>>(
      hb0, wx_b1, b_b1, z0);                    // z0 buffer reused as ZX1
  lstm_b1_wave_head<<<dim3(Bn), dim3(64), 0, stream>>>(
      x, z0, wh_b1, dw, db, out);
}

// Round 3
// 693.931 us; speedup vs baseline: 1.7967x; 1.7967x over previous
//
#include <hip/hip_runtime.h>
#include <hip/hip_bf16.h>

#define Bn 64
#define Tn 512
#define En 128
#define Hn 64
#define Gn 256   // 4*H
#define Cn 20

__device__ __forceinline__ float sigf(float x)      { return 1.f/(1.f+__expf(-x)); }
__device__ __forceinline__ float tanhfast(float x)  { return 2.f/(1.f+__expf(-2.f*x)) - 1.f; }

// ---------------------------------------------------------------------------
// Kernel A: Z0[b*T+t][j] = (word_emb[ids[b,t]] + pos_emb[t]) @ Wx_b0 + b_b0
// ---------------------------------------------------------------------------
__global__ __launch_bounds__(256, 1) void emb_proj_kernel(
    const int* __restrict__ x, const float* __restrict__ word_emb,
    const float* __restrict__ pos_emb, const float* __restrict__ wx,
    const float* __restrict__ bias, float* __restrict__ z0)
{
  __shared__ float emb[64][En];     // 32 KB
  __shared__ float wxl[32][Gn];     // 32 KB
  const int tid  = threadIdx.x;
  const int row0 = blockIdx.x * 64;

  #pragma unroll
  for (int it = 0; it < 8; ++it) {
    int idx = it*256 + tid;
    int rr  = idx >> 5;
    int e4  = (idx & 31) << 2;
    int r   = row0 + rr;
    int b   = r >> 9;
    int t   = r & (Tn-1);
    int id  = x[b*3*Tn + t];
    float4 we = *reinterpret_cast<const float4*>(&word_emb[(size_t)id*En + e4]);
    float4 pe = *reinterpret_cast<const float4*>(&pos_emb[(size_t)t*En + e4]);
    *reinterpret_cast<float4*>(&emb[rr][e4]) =
        make_float4(we.x+pe.x, we.y+pe.y, we.z+pe.z, we.w+pe.w);
  }

  const int jc = tid & 63;
  const int rg = tid >> 6;
  float acc[16][4];
  float4 bb = *reinterpret_cast<const float4*>(&bias[jc*4]);
  #pragma unroll
  for (int r = 0; r < 16; ++r) { acc[r][0]=bb.x; acc[r][1]=bb.y; acc[r][2]=bb.z; acc[r][3]=bb.w; }

  for (int ec = 0; ec < 4; ++ec) {
    __syncthreads();
    #pragma unroll
    for (int it = 0; it < 8; ++it) {
      int idx = it*256 + tid;
      int ee  = idx >> 6;
      int j4  = (idx & 63) << 2;
      *reinterpret_cast<float4*>(&wxl[ee][j4]) =
          *reinterpret_cast<const float4*>(&wx[(size_t)(ec*32+ee)*Gn + j4]);
    }
    __syncthreads();
    for (int ee = 0; ee < 32; ++ee) {
      float4 w = *reinterpret_cast<const float4*>(&wxl[ee][jc*4]);
      #pragma unroll
      for (int r = 0; r < 16; ++r) {
        float xv = emb[rg*16+r][ec*32+ee];
        acc[r][0] = fmaf(xv, w.x, acc[r][0]);
        acc[r][1] = fmaf(xv, w.y, acc[r][1]);
        acc[r][2] = fmaf(xv, w.z, acc[r][2]);
        acc[r][3] = fmaf(xv, w.w, acc[r][3]);
      }
    }
  }
  #pragma unroll
  for (int r = 0; r < 16; ++r) {
    size_t row = (size_t)row0 + rg*16 + r;
    *reinterpret_cast<float4*>(&z0[row*Gn + jc*4]) =
        make_float4(acc[r][0], acc[r][1], acc[r][2], acc[r][3]);
  }
}

// ---------------------------------------------------------------------------
// Kernel A2: ZX1[b*T+t][j] = hb0[b,t,:] @ Wx_b1 + b_b1
// ---------------------------------------------------------------------------
__global__ __launch_bounds__(256, 1) void zx1_gemm_kernel(
    const float* __restrict__ hb0, const float* __restrict__ wx,
    const float* __restrict__ bias, float* __restrict__ zx1)
{
  __shared__ float xl[64][Hn];
  __shared__ float wl[32][Gn];
  const int tid  = threadIdx.x;
  const int row0 = blockIdx.x * 64;

  #pragma unroll
  for (int it = 0; it < 4; ++it) {
    int idx = it*256 + tid;
    int rr  = idx >> 4;
    int e4  = (idx & 15) << 2;
    *reinterpret_cast<float4*>(&xl[rr][e4]) =
        *reinterpret_cast<const float4*>(&hb0[((size_t)row0+rr)*Hn + e4]);
  }

  const int jc = tid & 63;
  const int rg = tid >> 6;
  float acc[16][4];
  float4 bb = *reinterpret_cast<const float4*>(&bias[jc*4]);
  #pragma unroll
  for (int r = 0; r < 16; ++r) { acc[r][0]=bb.x; acc[r][1]=bb.y; acc[r][2]=bb.z; acc[r][3]=bb.w; }

  for (int kc = 0; kc < 2; ++kc) {
    __syncthreads();
    #pragma unroll
    for (int it = 0; it < 8; ++it) {
      int idx = it*256 + tid;
      int kk  = idx >> 6;
      int j4  = (idx & 63) << 2;
      *reinterpret_cast<float4*>(&wl[kk][j4]) =
          *reinterpret_cast<const float4*>(&wx[(size_t)(kc*32+kk)*Gn + j4]);
    }
    __syncthreads();
    for (int kk = 0; kk < 32; ++kk) {
      float4 w = *reinterpret_cast<const float4*>(&wl[kk][jc*4]);
      #pragma unroll
      for (int r = 0; r < 16; ++r) {
        float xv = xl[rg*16+r][kc*32+kk];
        acc[r][0] = fmaf(xv, w.x, acc[r][0]);
        acc[r][1] = fmaf(xv, w.y, acc[r][1]);
        acc[r][2] = fmaf(xv, w.z, acc[r][2]);
        acc[r][3] = fmaf(xv, w.w, acc[r][3]);
      }
    }
  }
  #pragma unroll
  for (int r = 0; r < 16; ++r) {
    size_t row = (size_t)row0 + rg*16 + r;
    *reinterpret_cast<float4*>(&zx1[row*Gn + jc*4]) =
        make_float4(acc[r][0], acc[r][1], acc[r][2], acc[r][3]);
  }
}

// ---------------------------------------------------------------------------
// Fast recurrence: 256 threads / 4 waves per batch element.
// Thread tid owns gate column tid (64 weight regs). One RAW s_barrier per
// step (lgkm-only wait -> no vmcnt drain). Gates computed redundantly in all
// 4 waves (each wave keeps its own h copy) -> no second barrier. z rows
// register-prefetched depth 4.
// ---------------------------------------------------------------------------
#define WAVE_BARRIER()                                        \
  do {                                                        \
    asm volatile("s_waitcnt lgkmcnt(0)" ::: "memory");        \
    __builtin_amdgcn_sched_barrier(0);                        \
    __builtin_amdgcn_s_barrier();                             \
    __builtin_amdgcn_sched_barrier(0);                        \
  } while (0)

template<bool IS_B0>
__global__ __launch_bounds__(256, 1) void lstm_fast(
    const int* __restrict__ x, const float* __restrict__ z,
    const float* __restrict__ wh, float* __restrict__ hb0,
    const float* __restrict__ dw, const float* __restrict__ db,
    float* __restrict__ out)
{
  const int b   = blockIdx.x;
  const int tid = threadIdx.x;
  const int wv  = tid >> 6;
  const int l   = tid & 63;

  __shared__ __align__(16) float z_s[2][Gn];
  __shared__ __align__(16) float h_own[4][Hn];
  __shared__ float sm[2][32];
  __shared__ int msk[Tn];

  float wcol[Hn];
  #pragma unroll
  for (int k = 0; k < Hn; ++k) wcol[k] = wh[(size_t)k*Gn + tid];

  for (int i = tid; i < Tn; i += 256) msk[i] = x[b*3*Tn + 2*Tn + i];
  h_own[wv][l] = 0.f;
  float c = 0.f, h = 0.f;
  const float* zr   = z + (size_t)b*Tn*Gn;
  float*       hout = hb0 + (size_t)b*Tn*Hn;
  __syncthreads();   // prologue only: msk + h_own visible to all waves

  // depth-4 register prefetch of this thread's z column
  float zpA, zpB, zpC, zpD;
  {
    int t0 = IS_B0 ? Tn-1 : 0;
    int t1 = IS_B0 ? Tn-2 : 1;
    int t2 = IS_B0 ? Tn-3 : 2;
    int t3 = IS_B0 ? Tn-4 : 3;
    zpA = zr[(size_t)t0*Gn + tid];
    zpB = zr[(size_t)t1*Gn + tid];
    zpC = zr[(size_t)t2*Gn + tid];
    zpD = zr[(size_t)t3*Gn + tid];
  }

#define STEP(s_, ZREG)                                                       \
  {                                                                          \
    const int t_ = IS_B0 ? (Tn-1-(s_)) : (s_);                               \
    const int mi = IS_B0 ? t_ : (Tn-1-t_);                                   \
    if (msk[mi]) {                                                           \
      float a0 = ZREG, a1 = 0.f, a2 = 0.f, a3 = 0.f;                         \
      _Pragma("unroll")                                                      \
      for (int k4 = 0; k4 < Hn/4; ++k4) {                                    \
        float4 hv = *reinterpret_cast<const float4*>(&h_own[wv][k4*4]);      \
        a0 = fmaf(hv.x, wcol[k4*4+0], a0);                                   \
        a1 = fmaf(hv.y, wcol[k4*4+1], a1);                                   \
        a2 = fmaf(hv.z, wcol[k4*4+2], a2);                                   \
        a3 = fmaf(hv.w, wcol[k4*4+3], a3);                                   \
      }                                                                      \
      z_s[(s_)&1][tid] = (a0+a1)+(a2+a3);                                    \
      WAVE_BARRIER();                                                        \
      float g0 = z_s[(s_)&1][l];                                             \
      float g1 = z_s[(s_)&1][Hn+l];                                          \
      float g2 = z_s[(s_)&1][2*Hn+l];                                        \
      float g3 = z_s[(s_)&1][3*Hn+l];                                        \
      float ig = sigf(g0), fg = sigf(g1);                                    \
      float gg = tanhfast(g2), og = sigf(g3);                                \
      c = fmaf(fg, c, ig*gg);                                                \
      h = og * tanhfast(c);                                                  \
      h_own[wv][l] = h;                                                      \
    }                                                                        \
    if (IS_B0 && wv == 0) hout[(size_t)t_*Hn + l] = h;                       \
    {                                                                        \
      int tn_ = IS_B0 ? (t_-4) : (t_+4);                                     \
      tn_ = tn_ < 0 ? 0 : (tn_ > Tn-1 ? Tn-1 : tn_);                         \
      ZREG = zr[(size_t)tn_*Gn + tid];                                       \
    }                                                                        \
  }

  for (int s = 0; s < Tn; s += 4) {
    STEP(s+0, zpA);
    STEP(s+1, zpB);
    STEP(s+2, zpC);
    STEP(s+3, zpD);
  }
#undef STEP

  if (!IS_B0) {
    // head: logits (C=20) + softmax, wave 0 only (it has the final h copy)
    if (tid < Cn) {
      float lg = db[tid];
      #pragma unroll
      for (int k = 0; k < Hn; ++k) lg = fmaf(h_own[0][k], dw[k*Cn + tid], lg);
      sm[0][tid] = lg;
    }
    if (tid < Cn) {
      float m = sm[0][0];
      #pragma unroll
      for (int k = 1; k < Cn; ++k) m = fmaxf(m, sm[0][k]);
      float e = __expf(sm[0][tid] - m);
      sm[1][tid] = e;
      float ssum = 0.f;
      #pragma unroll
      for (int k = 0; k < Cn; ++k) ssum += sm[1][k];
      out[b*Cn + tid] = e / ssum;
    }
  }
}

// ---------------------------------------------------------------------------
extern "C" void kernel_launch(void* const* d_in, const int* in_sizes, int n_in,
                              void* d_out, int out_size, void* d_ws, size_t ws_size,
                              hipStream_t stream)
{
  const int*   x        = (const int*)  d_in[0];
  const float* word_emb = (const float*)d_in[1];
  const float* pos_emb  = (const float*)d_in[2];
  // forward-branch weights d_in[3..8] are dead code in the reference
  const float* wx_b0    = (const float*)d_in[9];
  const float* wh_b0    = (const float*)d_in[10];
  const float* b_b0     = (const float*)d_in[11];
  const float* wx_b1    = (const float*)d_in[12];
  const float* wh_b1    = (const float*)d_in[13];
  const float* b_b1     = (const float*)d_in[14];
  const float* dw       = (const float*)d_in[15];
  const float* db       = (const float*)d_in[16];
  float* out = (float*)d_out;

  float* z0  = (float*)d_ws;                    // B*T*256 f32 = 33.5 MB (reused as ZX1)
  float* hb0 = z0 + (size_t)Bn*Tn*Gn;           // B*T*64  f32 =  8.4 MB

  emb_proj_kernel<<<dim3((Bn*Tn)/64), dim3(256), 0, stream>>>(
      x, word_emb, pos_emb, wx_b0, b_b0, z0);
  lstm_fast<true><<<dim3(Bn), dim3(256), 0, stream>>>(
      x, z0, wh_b0, hb0, nullptr, nullptr, nullptr);
  zx1_gemm_kernel<<<dim3((Bn*Tn)/64), dim3(256), 0, stream>>>(
      hb0, wx_b1, b_b1, z0);                    // z0 buffer reused as ZX1
  lstm_fast<false><<<dim3(Bn), dim3(256), 0, stream>>>(
      x, z0, wh_b1, hb0, dw, db, out);
}